// Round 10
// baseline (492.999 us; speedup 1.0000x reference)
//
#include <hip/hip_runtime.h>
#include <math.h>

#define NN 768
#define CS 384
#define CZ 128
#define CH 16
#define HH 12
#define PQ 4
#define PV 8
#define OUTIN 2112

#define SC_QK 0.14433756729740643f   // sqrt(1/(3*16))
#define SC_B  0.57735026918962576f   // sqrt(1/3)
#define SC_HW 0.13608276348795434f   // sqrt(2/(27*4))
#define MSLACK 12.0f                 // safe-softmax headroom over lqd row max

// ---------------- Kernel A: input projections (s @ W.T + b) ----------------
__global__ __launch_bounds__(256) void kproj(
    const float* __restrict__ s,
    const float* __restrict__ Wq,  const float* __restrict__ bq,
    const float* __restrict__ Wkv, const float* __restrict__ bkv,
    const float* __restrict__ Wqp, const float* __restrict__ bqp,
    const float* __restrict__ Wkvp,const float* __restrict__ bkvp,
    float* __restrict__ q, float* __restrict__ kT, float* __restrict__ vallT,
    float* __restrict__ qpr, float* __restrict__ kvpr)
{
    __shared__ float s_lds[8*384];
    int n0 = blockIdx.x * 8;
    int t = threadIdx.x;
    for (int idx = t; idx < 8*384; idx += 256)
        s_lds[idx] = s[(n0 + idx/384)*384 + (idx%384)];
    __syncthreads();

    int o = blockIdx.y * 128 + (t & 127);
    int ng = t >> 7;
    const float* wrow; float bias;
    if (o < 192)      { wrow = Wq   + o*384;       bias = bq[o]; }
    else if (o < 576) { wrow = Wkv  + (o-192)*384; bias = bkv[o-192]; }
    else if (o < 720) { wrow = Wqp  + (o-576)*384; bias = bqp[o-576]; }
    else              { wrow = Wkvp + (o-720)*384; bias = bkvp[o-720]; }

    float acc[4] = {bias, bias, bias, bias};
    const float4* wr4 = reinterpret_cast<const float4*>(wrow);
    for (int c4 = 0; c4 < 96; ++c4) {
        float4 w = wr4[c4];
        #pragma unroll
        for (int nn = 0; nn < 4; ++nn) {
            const float* sr = &s_lds[(ng*4+nn)*384 + c4*4];
            acc[nn] = fmaf(w.x, sr[0], acc[nn]);
            acc[nn] = fmaf(w.y, sr[1], acc[nn]);
            acc[nn] = fmaf(w.z, sr[2], acc[nn]);
            acc[nn] = fmaf(w.w, sr[3], acc[nn]);
        }
    }
    #pragma unroll
    for (int nn = 0; nn < 4; ++nn) {
        int n = n0 + ng*4 + nn;
        float v = acc[nn];
        if (o < 192)      q[n*192 + o] = v;
        else if (o < 576) {
            int oo = o - 192, h = oo >> 5, cc = oo & 31;
            if (cc < 16) kT[(h*NN + n)*16 + cc] = v;
            else         vallT[(size_t)(h*40 + (cc-16))*NN + n] = v;
        }
        else if (o < 720) qpr[n*144 + (o-576)] = v;
        else              kvpr[n*432 + (o-720)] = v;
    }
}

// ---------------- Kernel B: apply frames (rot, trans) to points ----------------
__global__ __launch_bounds__(192) void krot(
    const float* __restrict__ rot, const float* __restrict__ trans,
    const float* __restrict__ qpr, const float* __restrict__ kvpr,
    float* __restrict__ qp, float* __restrict__ kpT, float* __restrict__ vallT)
{
    int n = blockIdx.x;
    __shared__ float R[9], T[3];
    int t = threadIdx.x;
    if (t < 9) R[t] = rot[n*9 + t];
    if (t < 3) T[t] = trans[n*3 + t];
    __syncthreads();

    const float* src = (t < 48) ? (qpr + n*144 + t*3) : (kvpr + n*432 + (t-48)*3);
    float x = src[0], y = src[1], z = src[2];
    float wx = R[0]*x + R[1]*y + R[2]*z + T[0];
    float wy = R[3]*x + R[4]*y + R[5]*z + T[1];
    float wz = R[6]*x + R[7]*y + R[8]*z + T[2];
    if (t < 48) {
        float* d = qp + n*144 + t*3;
        d[0]=wx; d[1]=wy; d[2]=wz;
    } else {
        int pi = t - 48, h = pi/12, pp = pi%12;
        if (pp < 4) {
            float* d = kpT + (h*NN+n)*12 + pp*3;
            d[0]=wx; d[1]=wy; d[2]=wz;
        } else {
            int ch = h*40 + 16 + (pp-4)*3;
            vallT[(size_t)(ch+0)*NN + n] = wx;
            vallT[(size_t)(ch+1)*NN + n] = wy;
            vallT[(size_t)(ch+2)*NN + n] = wz;
        }
    }
}

// ---------------- Kernel C1: z-independent logits + per-tile row max ----------------
__global__ __launch_bounds__(256) void kqk(
    const float* __restrict__ kT, const float* __restrict__ kpT,
    const float* __restrict__ q, const float* __restrict__ qp,
    const float* __restrict__ mask, const float* __restrict__ head_w,
    const float* __restrict__ bb, float* __restrict__ lqd,
    float* __restrict__ mpart)
{
    const int j0 = blockIdx.x * 64;
    const int i0 = blockIdx.y * 32;
    __shared__ float ktl[64][17], kpl[64][13];
    __shared__ float ql[32][17],  qpl[32][13];
    __shared__ float mi_l[32], mj_l[64];
    __shared__ float mpl[32][12];
    const int t = threadIdx.x;
    if (t < 32) mi_l[t] = mask[i0 + t];
    if (t < 64) mj_l[t] = mask[j0 + t];

    const int jl = t & 63, wv = t >> 6;

    for (int h = 0; h < 12; ++h) {
        __syncthreads();
        for (int idx = t; idx < 1024; idx += 256)
            ktl[idx >> 4][idx & 15] = kT[(size_t)(h*NN + j0 + (idx >> 4))*16 + (idx & 15)];
        for (int idx = t; idx < 768; idx += 256) {
            int r = idx / 12, e = idx - r*12;
            kpl[r][e] = kpT[(size_t)(h*NN + j0 + r)*12 + e];
        }
        for (int idx = t; idx < 512; idx += 256)
            ql[idx >> 4][idx & 15] = q[(i0 + (idx >> 4))*192 + h*16 + (idx & 15)];
        for (int idx = t; idx < 384; idx += 256) {
            int r = idx / 12, e = idx - r*12;
            qpl[r][e] = qp[(i0 + r)*144 + h*12 + e];
        }
        __syncthreads();

        const float hwh = log1pf(expf(head_w[h])) * SC_HW;
        const float bbh = bb[h] * SC_B;
        const float mj = mj_l[jl];
        #pragma unroll
        for (int k = 0; k < 8; ++k) {
            const int il = wv*8 + k;
            float qk = 0.f;
            #pragma unroll
            for (int c = 0; c < 16; ++c) qk = fmaf(ktl[jl][c], ql[il][c], qk);
            float d2 = 0.f;
            #pragma unroll
            for (int e = 0; e < 12; ++e) { float d = qpl[il][e] - kpl[jl][e]; d2 = fmaf(d, d, d2); }
            float mt = 1e9f * (mi_l[il]*mj - 1.0f);
            float lg = fmaf(qk, SC_QK, fmaf(-0.5f*hwh, d2, bbh)) + mt;
            lqd[((size_t)(i0+il)*NN + j0 + jl)*12 + h] = lg;
            float m = lg;
            m = fmaxf(m, __shfl_xor(m, 1, 64));
            m = fmaxf(m, __shfl_xor(m, 2, 64));
            m = fmaxf(m, __shfl_xor(m, 4, 64));
            m = fmaxf(m, __shfl_xor(m, 8, 64));
            m = fmaxf(m, __shfl_xor(m, 16, 64));
            m = fmaxf(m, __shfl_xor(m, 32, 64));
            if (jl == 0) mpl[il][h] = m;
        }
    }
    __syncthreads();
    if (t < 384) {
        int il = t / 12, h = t - il*12;
        mpart[((size_t)h*NN + i0 + il)*12 + blockIdx.x] = mpl[il][h];
    }
}

// ---------------- Kernel C2: p = exp(lqd + SC_B*(z·Wb) - M) IN PLACE; seg sums ----------------
__global__ __launch_bounds__(256, 6) void kpexp(
    const float* __restrict__ z, const float* __restrict__ Wb,
    const float* __restrict__ mpart, float* __restrict__ p_io,
    float* __restrict__ ssum)
{
    __shared__ float M_lds[12];
    __shared__ float sred[4][12];
    const int i = blockIdx.x, jseg = blockIdx.y;
    const int t = threadIdx.x, w = t >> 6, l = t & 63;
    if (t < 12) {
        const float4* mp = (const float4*)(mpart + ((size_t)t*NN + i)*12);
        float4 a = mp[0], b = mp[1], c = mp[2];
        float m = fmaxf(fmaxf(fmaxf(a.x,a.y), fmaxf(a.z,a.w)),
                 fmaxf(fmaxf(fmaxf(b.x,b.y), fmaxf(b.z,b.w)),
                       fmaxf(fmaxf(c.x,c.y), fmaxf(c.z,c.w))));
        M_lds[t] = m + MSLACK;
    }
    __syncthreads();

    const int j = jseg*256 + t;
    const float4* __restrict__ zr4 = (const float4*)(z + ((size_t)i*NN + j)*CZ);
    const float4* __restrict__ wb4 = (const float4*)Wb;   // uniform -> s_load

    float b0=0,b1=0,b2=0,b3=0,b4=0,b5=0,b6=0,b7=0,b8=0,b9=0,b10=0,b11=0;
    #define HD(B, H) { float4 wv = wb4[(H)*32 + c4]; \
        B = fmaf(zv.x, wv.x, B); B = fmaf(zv.y, wv.y, B); \
        B = fmaf(zv.z, wv.z, B); B = fmaf(zv.w, wv.w, B); }
    #pragma unroll 4
    for (int c4 = 0; c4 < 32; ++c4) {
        float4 zv = zr4[c4];
        HD(b0,0) HD(b1,1) HD(b2,2)  HD(b3,3)  HD(b4,4)   HD(b5,5)
        HD(b6,6) HD(b7,7) HD(b8,8)  HD(b9,9)  HD(b10,10) HD(b11,11)
    }
    #undef HD

    float* gp = p_io + ((size_t)i*NN + j)*12;
    float4 qa = *(const float4*)(gp + 0);
    float4 qb = *(const float4*)(gp + 4);
    float4 qc = *(const float4*)(gp + 8);
    float p0  = __expf(fmaf(b0,  SC_B, qa.x) - M_lds[0]);
    float p1  = __expf(fmaf(b1,  SC_B, qa.y) - M_lds[1]);
    float p2  = __expf(fmaf(b2,  SC_B, qa.z) - M_lds[2]);
    float p3  = __expf(fmaf(b3,  SC_B, qa.w) - M_lds[3]);
    float p4  = __expf(fmaf(b4,  SC_B, qb.x) - M_lds[4]);
    float p5  = __expf(fmaf(b5,  SC_B, qb.y) - M_lds[5]);
    float p6  = __expf(fmaf(b6,  SC_B, qb.z) - M_lds[6]);
    float p7  = __expf(fmaf(b7,  SC_B, qb.w) - M_lds[7]);
    float p8  = __expf(fmaf(b8,  SC_B, qc.x) - M_lds[8]);
    float p9  = __expf(fmaf(b9,  SC_B, qc.y) - M_lds[9]);
    float p10 = __expf(fmaf(b10, SC_B, qc.z) - M_lds[10]);
    float p11 = __expf(fmaf(b11, SC_B, qc.w) - M_lds[11]);
    float4 oa; oa.x = p0; oa.y = p1;  oa.z = p2;  oa.w = p3;
    float4 ob; ob.x = p4; ob.y = p5;  ob.z = p6;  ob.w = p7;
    float4 oc; oc.x = p8; oc.y = p9;  oc.z = p10; oc.w = p11;
    *(float4*)(gp + 0) = oa;
    *(float4*)(gp + 4) = ob;
    *(float4*)(gp + 8) = oc;

    #define RED(P) { P += __shfl_xor(P, 1, 64);  P += __shfl_xor(P, 2, 64); \
                     P += __shfl_xor(P, 4, 64);  P += __shfl_xor(P, 8, 64); \
                     P += __shfl_xor(P, 16, 64); P += __shfl_xor(P, 32, 64); }
    RED(p0) RED(p1) RED(p2) RED(p3) RED(p4)  RED(p5)
    RED(p6) RED(p7) RED(p8) RED(p9) RED(p10) RED(p11)
    #undef RED
    if (l == 0) {
        sred[w][0] = p0; sred[w][1] = p1; sred[w][2]  = p2;  sred[w][3]  = p3;
        sred[w][4] = p4; sred[w][5] = p5; sred[w][6]  = p6;  sred[w][7]  = p7;
        sred[w][8] = p8; sred[w][9] = p9; sred[w][10] = p10; sred[w][11] = p11;
    }
    __syncthreads();
    if (t < 12)
        ssum[(size_t)jseg*(12*NN) + t*NN + i] =
            sred[0][t] + sred[1][t] + sred[2][t] + sred[3][t];
}

// ---------------- Kernel C3a: o_pair = p @ z, no LDS staging ----------------
// grid (768 i, 4 ch-quads of 32). Wave = j-segment of 192; lane = (jo 0..7, c4 0..7).
// 12-head float4 accumulators per lane; p read from global (L1-broadcast), z coalesced.
__global__ __launch_bounds__(256) void kfinB(
    const float* __restrict__ z, const float* __restrict__ p,
    const float* __restrict__ ssum, float* __restrict__ cat)
{
    __shared__ float4 opart[4][12][8];
    __shared__ float sinv[12];
    const int i = blockIdx.x, qq = blockIdx.y;
    const int t = threadIdx.x, w = t >> 6, l = t & 63;
    const int jo = l >> 3, c4 = l & 7;
    if (t < 12)
        sinv[t] = 1.0f / (ssum[t*NN + i] + ssum[12*NN + t*NN + i] + ssum[24*NN + t*NN + i]);

    float4 a0={0,0,0,0},a1={0,0,0,0},a2={0,0,0,0},a3={0,0,0,0};
    float4 a4={0,0,0,0},a5={0,0,0,0},a6={0,0,0,0},a7={0,0,0,0};
    float4 a8={0,0,0,0},a9={0,0,0,0},a10={0,0,0,0},a11={0,0,0,0};

    const float4* __restrict__ zb = (const float4*)(z + (size_t)i*NN*CZ) + qq*8 + c4;
    const float4* __restrict__ pb = (const float4*)(p + (size_t)i*NN*12);

    #pragma unroll 2
    for (int jb = 0; jb < 24; ++jb) {
        const int j = w*192 + jb*8 + jo;
        float4 zv = zb[(size_t)j*32];
        float4 pa = pb[j*3 + 0];
        float4 pc = pb[j*3 + 1];
        float4 pe = pb[j*3 + 2];
        #define ACC(A, PS) { A.x = fmaf(PS, zv.x, A.x); A.y = fmaf(PS, zv.y, A.y); \
                             A.z = fmaf(PS, zv.z, A.z); A.w = fmaf(PS, zv.w, A.w); }
        ACC(a0, pa.x) ACC(a1, pa.y) ACC(a2,  pa.z) ACC(a3,  pa.w)
        ACC(a4, pc.x) ACC(a5, pc.y) ACC(a6,  pc.z) ACC(a7,  pc.w)
        ACC(a8, pe.x) ACC(a9, pe.y) ACC(a10, pe.z) ACC(a11, pe.w)
        #undef ACC
    }

    // fold across jo (lane bits 3..5)
    #define FOLD(V) { \
        V.x += __shfl_xor(V.x, 8, 64);  V.y += __shfl_xor(V.y, 8, 64);  \
        V.z += __shfl_xor(V.z, 8, 64);  V.w += __shfl_xor(V.w, 8, 64);  \
        V.x += __shfl_xor(V.x, 16, 64); V.y += __shfl_xor(V.y, 16, 64); \
        V.z += __shfl_xor(V.z, 16, 64); V.w += __shfl_xor(V.w, 16, 64); \
        V.x += __shfl_xor(V.x, 32, 64); V.y += __shfl_xor(V.y, 32, 64); \
        V.z += __shfl_xor(V.z, 32, 64); V.w += __shfl_xor(V.w, 32, 64); }
    FOLD(a0) FOLD(a1) FOLD(a2) FOLD(a3) FOLD(a4) FOLD(a5)
    FOLD(a6) FOLD(a7) FOLD(a8) FOLD(a9) FOLD(a10) FOLD(a11)
    #undef FOLD
    if (jo == 0) {
        opart[w][0][c4] = a0;   opart[w][1][c4] = a1;
        opart[w][2][c4] = a2;   opart[w][3][c4] = a3;
        opart[w][4][c4] = a4;   opart[w][5][c4] = a5;
        opart[w][6][c4] = a6;   opart[w][7][c4] = a7;
        opart[w][8][c4] = a8;   opart[w][9][c4] = a9;
        opart[w][10][c4] = a10; opart[w][11][c4] = a11;
    }
    __syncthreads();
    if (t < 96) {
        const int h = t >> 3, cc = t & 7;
        float4 v0 = opart[0][h][cc], v1 = opart[1][h][cc];
        float4 v2 = opart[2][h][cc], v3 = opart[3][h][cc];
        const float sc = sinv[h];
        float4 o;
        o.x = (v0.x + v1.x + v2.x + v3.x) * sc;
        o.y = (v0.y + v1.y + v2.y + v3.y) * sc;
        o.z = (v0.z + v1.z + v2.z + v3.z) * sc;
        o.w = (v0.w + v1.w + v2.w + v3.w) * sc;
        *(float4*)(cat + (size_t)i*OUTIN + 576 + h*128 + qq*32 + cc*4) = o;
    }
}

// ---------------- Kernel C3b: o / o_pt = p @ vallT + rotate/norm epilogue ----------------
__global__ __launch_bounds__(256, 4) void kfinC(
    const float* __restrict__ vallT, const float* __restrict__ p,
    const float* __restrict__ ssum,
    const float* __restrict__ rot, const float* __restrict__ trans,
    float* __restrict__ cat)
{
    __shared__ float an_l[12][776];
    __shared__ float sinv[12];
    __shared__ float optl[12][24];
    __shared__ float R[9], T[3];
    const int i = blockIdx.x;
    const int t = threadIdx.x, w = t >> 6, l = t & 63;
    if (t < 9) R[t] = rot[i*9 + t];
    if (t < 3) T[t] = trans[i*3 + t];
    if (t >= 16 && t < 28) {
        const int h = t - 16;
        sinv[h] = 1.0f / (ssum[h*NN + i] + ssum[12*NN + h*NN + i] + ssum[24*NN + h*NN + i]);
    }

    const float4* pr4 = (const float4*)(p + (size_t)i*NN*12);
    #pragma unroll
    for (int jj = 0; jj < 3; ++jj) {
        const int j = jj*256 + t;
        float4 ga = pr4[j*3 + 0];
        float4 gb = pr4[j*3 + 1];
        float4 gc = pr4[j*3 + 2];
        an_l[0][j] = ga.x;  an_l[1][j] = ga.y;  an_l[2][j]  = ga.z;  an_l[3][j]  = ga.w;
        an_l[4][j] = gb.x;  an_l[5][j] = gb.y;  an_l[6][j]  = gb.z;  an_l[7][j]  = gb.w;
        an_l[8][j] = gc.x;  an_l[9][j] = gc.y;  an_l[10][j] = gc.z;  an_l[11][j] = gc.w;
    }
    __syncthreads();

    float* crow = cat + (size_t)i*OUTIN;
    for (int cc = 0; cc < 120; ++cc) {
        const int ch = w*120 + cc;
        const int h = ch / 40, e = ch % 40;
        const float2* __restrict__ vr = (const float2*)(vallT + (size_t)ch*NN);
        const float2* __restrict__ pr = (const float2*)(&an_l[h][0]);
        float ax = 0.f, ay = 0.f;
        #pragma unroll
        for (int jc = 0; jc < 6; ++jc) {
            float2 v = vr[jc*64 + l];
            float2 pp = pr[jc*64 + l];
            ax = fmaf(pp.x, v.x, ax);
            ay = fmaf(pp.y, v.y, ay);
        }
        float sv = ax + ay;
        #pragma unroll
        for (int off = 32; off >= 1; off >>= 1) sv += __shfl_xor(sv, off, 64);
        if (l == 0) {
            float val = sv * sinv[h];
            if (e < 16) crow[h*16 + e] = val;
            else        optl[h][e-16] = val;
        }
    }
    __syncthreads();
    if (t < 96) {
        int h = t >> 3, pp = t & 7;
        float wx = optl[h][pp*3+0] - T[0];
        float wy = optl[h][pp*3+1] - T[1];
        float wz = optl[h][pp*3+2] - T[2];
        crow[192 + 0*96 + h*8 + pp] = R[0]*wx + R[3]*wy + R[6]*wz;
        crow[192 + 1*96 + h*8 + pp] = R[1]*wx + R[4]*wy + R[7]*wz;
        crow[192 + 2*96 + h*8 + pp] = R[2]*wx + R[5]*wy + R[8]*wz;
        crow[480 + h*8 + pp] = sqrtf(fmaf(wx,wx,fmaf(wy,wy,wz*wz)) + 1e-8f);
    }
}

// ---------------- Kernel D1: out partial = cat-tile @ Wout-tile^T (split-K) ----------------
__global__ __launch_bounds__(256) void koutp(
    const float* __restrict__ cat, const float* __restrict__ Wout,
    float* __restrict__ ptmp)
{
    __shared__ float ct[32][36];
    __shared__ float wt[64][36];
    const int n0 = blockIdx.x * 32, o0 = blockIdx.y * 64;
    const int k0 = blockIdx.z * 352;
    const int t = threadIdx.x;
    const int tn = (t >> 4) * 2;
    const int to = t & 15;

    float a00=0,a01=0,a02=0,a03=0, a10=0,a11=0,a12=0,a13=0;

    for (int c = 0; c < 11; ++c) {
        __syncthreads();
        #pragma unroll
        for (int u = 0; u < 4; ++u) {
            int idx = u*256 + t, r = idx >> 5, cc = idx & 31;
            ct[r][cc] = cat[(size_t)(n0 + r)*OUTIN + k0 + c*32 + cc];
        }
        #pragma unroll
        for (int u = 0; u < 8; ++u) {
            int idx = u*256 + t, r = idx >> 5, cc = idx & 31;
            wt[r][cc] = Wout[(size_t)(o0 + r)*OUTIN + k0 + c*32 + cc];
        }
        __syncthreads();
        #pragma unroll
        for (int kk = 0; kk < 32; kk += 4) {
            float4 c0 = *(const float4*)&ct[tn][kk];
            float4 c1 = *(const float4*)&ct[tn+1][kk];
            float4 w0 = *(const float4*)&wt[to][kk];
            float4 w1 = *(const float4*)&wt[to+16][kk];
            float4 w2 = *(const float4*)&wt[to+32][kk];
            float4 w3 = *(const float4*)&wt[to+48][kk];
            a00 = fmaf(c0.x,w0.x,a00); a00 = fmaf(c0.y,w0.y,a00); a00 = fmaf(c0.z,w0.z,a00); a00 = fmaf(c0.w,w0.w,a00);
            a01 = fmaf(c0.x,w1.x,a01); a01 = fmaf(c0.y,w1.y,a01); a01 = fmaf(c0.z,w1.z,a01); a01 = fmaf(c0.w,w1.w,a01);
            a02 = fmaf(c0.x,w2.x,a02); a02 = fmaf(c0.y,w2.y,a02); a02 = fmaf(c0.z,w2.z,a02); a02 = fmaf(c0.w,w2.w,a02);
            a03 = fmaf(c0.x,w3.x,a03); a03 = fmaf(c0.y,w3.y,a03); a03 = fmaf(c0.z,w3.z,a03); a03 = fmaf(c0.w,w3.w,a03);
            a10 = fmaf(c1.x,w0.x,a10); a10 = fmaf(c1.y,w0.y,a10); a10 = fmaf(c1.z,w0.z,a10); a10 = fmaf(c1.w,w0.w,a10);
            a11 = fmaf(c1.x,w1.x,a11); a11 = fmaf(c1.y,w1.y,a11); a11 = fmaf(c1.z,w1.z,a11); a11 = fmaf(c1.w,w1.w,a11);
            a12 = fmaf(c1.x,w2.x,a12); a12 = fmaf(c1.y,w2.y,a12); a12 = fmaf(c1.z,w2.z,a12); a12 = fmaf(c1.w,w2.w,a12);
            a13 = fmaf(c1.x,w3.x,a13); a13 = fmaf(c1.y,w3.y,a13); a13 = fmaf(c1.z,w3.z,a13); a13 = fmaf(c1.w,w3.w,a13);
        }
    }
    float* pb = ptmp + (size_t)blockIdx.z * (NN*384);
    pb[(size_t)(n0+tn+0)*384 + o0+to+ 0] = a00;
    pb[(size_t)(n0+tn+0)*384 + o0+to+16] = a01;
    pb[(size_t)(n0+tn+0)*384 + o0+to+32] = a02;
    pb[(size_t)(n0+tn+0)*384 + o0+to+48] = a03;
    pb[(size_t)(n0+tn+1)*384 + o0+to+ 0] = a10;
    pb[(size_t)(n0+tn+1)*384 + o0+to+16] = a11;
    pb[(size_t)(n0+tn+1)*384 + o0+to+32] = a12;
    pb[(size_t)(n0+tn+1)*384 + o0+to+48] = a13;
}

// ---------------- Kernel D2: reduce split-K partials + bias ----------------
__global__ __launch_bounds__(256) void kred(
    const float* __restrict__ ptmp, const float* __restrict__ bout,
    float* __restrict__ out)
{
    int idx = blockIdx.x * 256 + threadIdx.x;
    int o = idx % 384;
    float v = bout[o];
    #pragma unroll
    for (int s = 0; s < 6; ++s) v += ptmp[(size_t)s*(NN*384) + idx];
    out[idx] = v;
}

extern "C" void kernel_launch(void* const* d_in, const int* in_sizes, int n_in,
                              void* d_out, int out_size, void* d_ws, size_t ws_size,
                              hipStream_t stream) {
    const float* s      = (const float*)d_in[0];
    const float* z      = (const float*)d_in[1];
    const float* rot    = (const float*)d_in[2];
    const float* trans  = (const float*)d_in[3];
    const float* mask   = (const float*)d_in[4];
    const float* Wq     = (const float*)d_in[5];
    const float* bq     = (const float*)d_in[6];
    const float* Wkv    = (const float*)d_in[7];
    const float* bkv    = (const float*)d_in[8];
    const float* Wqp    = (const float*)d_in[9];
    const float* bqp    = (const float*)d_in[10];
    const float* Wkvp   = (const float*)d_in[11];
    const float* bkvp   = (const float*)d_in[12];
    const float* Wb     = (const float*)d_in[13];
    const float* bb     = (const float*)d_in[14];
    const float* head_w = (const float*)d_in[15];
    const float* Wout   = (const float*)d_in[16];
    const float* bout   = (const float*)d_in[17];
    float* out = (float*)d_out;
    float* ws  = (float*)d_ws;

    float* q     = ws;              // 147456
    float* kT    = ws + 147456;     // 147456
    float* kpT   = ws + 294912;     // 110592
    float* vallT = ws + 405504;     // 368640
    float* qp    = ws + 774144;     // 110592
    float* qpr   = ws + 884736;     // 110592
    float* kvpr  = ws + 995328;     // 331776
    float* mpart = ws + 1327104;    // 110592
    float* ssum  = ws + 1437696;    // 27648
    float* cat   = ws + 1465344;    // 1622016
    float* lqd   = ws + 3087360;    // 7077888 [i][j][12]; p written in place
    float* ptmp  = ws + 10165248;   // 1769472

    kproj<<<dim3(96, 9), 256, 0, stream>>>(s, Wq, bq, Wkv, bkv, Wqp, bqp, Wkvp, bkvp,
                                           q, kT, vallT, qpr, kvpr);
    krot<<<dim3(768), 192, 0, stream>>>(rot, trans, qpr, kvpr, qp, kpT, vallT);
    kqk<<<dim3(12, 24), 256, 0, stream>>>(kT, kpT, q, qp, mask, head_w, bb, lqd, mpart);
    kpexp<<<dim3(768, 3), 256, 0, stream>>>(z, Wb, mpart, lqd, ssum);
    kfinB<<<dim3(768, 4), 256, 0, stream>>>(z, lqd, ssum, cat);
    kfinC<<<dim3(768), 256, 0, stream>>>(vallT, lqd, ssum, rot, trans, cat);
    koutp<<<dim3(24, 6, 6), 256, 0, stream>>>(cat, Wout, ptmp);
    kred<<<dim3(1152), 256, 0, stream>>>(ptmp, bout, out);
}

// Round 11
// 424.110 us; speedup vs baseline: 1.1624x; 1.1624x over previous
//
#include <hip/hip_runtime.h>
#include <math.h>

#define NN 768
#define CS 384
#define CZ 128
#define CH 16
#define HH 12
#define PQ 4
#define PV 8
#define OUTIN 2112

#define SC_QK 0.14433756729740643f   // sqrt(1/(3*16))
#define SC_B  0.57735026918962576f   // sqrt(1/3)
#define SC_HW 0.13608276348795434f   // sqrt(2/(27*4))
#define MSLACK 12.0f                 // safe-softmax headroom over lqd row max

// ---------------- Kernel A: input projections (s @ W.T + b) ----------------
__global__ __launch_bounds__(256) void kproj(
    const float* __restrict__ s,
    const float* __restrict__ Wq,  const float* __restrict__ bq,
    const float* __restrict__ Wkv, const float* __restrict__ bkv,
    const float* __restrict__ Wqp, const float* __restrict__ bqp,
    const float* __restrict__ Wkvp,const float* __restrict__ bkvp,
    float* __restrict__ q, float* __restrict__ kT, float* __restrict__ vall,
    float* __restrict__ qpr, float* __restrict__ kvpr)
{
    __shared__ float s_lds[8*384];
    int n0 = blockIdx.x * 8;
    int t = threadIdx.x;
    for (int idx = t; idx < 8*384; idx += 256)
        s_lds[idx] = s[(n0 + idx/384)*384 + (idx%384)];
    __syncthreads();

    int o = blockIdx.y * 128 + (t & 127);
    int ng = t >> 7;
    const float* wrow; float bias;
    if (o < 192)      { wrow = Wq   + o*384;       bias = bq[o]; }
    else if (o < 576) { wrow = Wkv  + (o-192)*384; bias = bkv[o-192]; }
    else if (o < 720) { wrow = Wqp  + (o-576)*384; bias = bqp[o-576]; }
    else              { wrow = Wkvp + (o-720)*384; bias = bkvp[o-720]; }

    float acc[4] = {bias, bias, bias, bias};
    const float4* wr4 = reinterpret_cast<const float4*>(wrow);
    for (int c4 = 0; c4 < 96; ++c4) {
        float4 w = wr4[c4];
        #pragma unroll
        for (int nn = 0; nn < 4; ++nn) {
            const float* sr = &s_lds[(ng*4+nn)*384 + c4*4];
            acc[nn] = fmaf(w.x, sr[0], acc[nn]);
            acc[nn] = fmaf(w.y, sr[1], acc[nn]);
            acc[nn] = fmaf(w.z, sr[2], acc[nn]);
            acc[nn] = fmaf(w.w, sr[3], acc[nn]);
        }
    }
    #pragma unroll
    for (int nn = 0; nn < 4; ++nn) {
        int n = n0 + ng*4 + nn;
        float v = acc[nn];
        if (o < 192)      q[n*192 + o] = v;
        else if (o < 576) {
            int oo = o - 192, h = oo >> 5, cc = oo & 31;
            if (cc < 16) kT[(h*NN + n)*16 + cc] = v;
            else         vall[(size_t)n*480 + h*40 + (cc-16)] = v;
        }
        else if (o < 720) qpr[n*144 + (o-576)] = v;
        else              kvpr[n*432 + (o-720)] = v;
    }
}

// ---------------- Kernel B: apply frames (rot, trans) to points ----------------
__global__ __launch_bounds__(192) void krot(
    const float* __restrict__ rot, const float* __restrict__ trans,
    const float* __restrict__ qpr, const float* __restrict__ kvpr,
    float* __restrict__ qp, float* __restrict__ kpT, float* __restrict__ vall)
{
    int n = blockIdx.x;
    __shared__ float R[9], T[3];
    int t = threadIdx.x;
    if (t < 9) R[t] = rot[n*9 + t];
    if (t < 3) T[t] = trans[n*3 + t];
    __syncthreads();

    const float* src = (t < 48) ? (qpr + n*144 + t*3) : (kvpr + n*432 + (t-48)*3);
    float x = src[0], y = src[1], z = src[2];
    float wx = R[0]*x + R[1]*y + R[2]*z + T[0];
    float wy = R[3]*x + R[4]*y + R[5]*z + T[1];
    float wz = R[6]*x + R[7]*y + R[8]*z + T[2];
    if (t < 48) {
        float* d = qp + n*144 + t*3;
        d[0]=wx; d[1]=wy; d[2]=wz;
    } else {
        int pi = t - 48, h = pi/12, pp = pi%12;
        if (pp < 4) {
            float* d = kpT + (h*NN+n)*12 + pp*3;
            d[0]=wx; d[1]=wy; d[2]=wz;
        } else {
            float* d = vall + (size_t)n*480 + h*40 + 16 + (pp-4)*3;
            d[0]=wx; d[1]=wy; d[2]=wz;
        }
    }
}

// ---------------- Kernel C1: z-independent logits + per-tile row max ----------------
__global__ __launch_bounds__(256) void kqk(
    const float* __restrict__ kT, const float* __restrict__ kpT,
    const float* __restrict__ q, const float* __restrict__ qp,
    const float* __restrict__ mask, const float* __restrict__ head_w,
    const float* __restrict__ bb, float* __restrict__ lqd,
    float* __restrict__ mpart)
{
    const int j0 = blockIdx.x * 64;
    const int i0 = blockIdx.y * 32;
    __shared__ float ktl[64][17], kpl[64][13];
    __shared__ float ql[32][17],  qpl[32][13];
    __shared__ float mi_l[32], mj_l[64];
    __shared__ float mpl[32][12];
    const int t = threadIdx.x;
    if (t < 32) mi_l[t] = mask[i0 + t];
    if (t < 64) mj_l[t] = mask[j0 + t];

    const int jl = t & 63, wv = t >> 6;

    for (int h = 0; h < 12; ++h) {
        __syncthreads();
        for (int idx = t; idx < 1024; idx += 256)
            ktl[idx >> 4][idx & 15] = kT[(size_t)(h*NN + j0 + (idx >> 4))*16 + (idx & 15)];
        for (int idx = t; idx < 768; idx += 256) {
            int r = idx / 12, e = idx - r*12;
            kpl[r][e] = kpT[(size_t)(h*NN + j0 + r)*12 + e];
        }
        for (int idx = t; idx < 512; idx += 256)
            ql[idx >> 4][idx & 15] = q[(i0 + (idx >> 4))*192 + h*16 + (idx & 15)];
        for (int idx = t; idx < 384; idx += 256) {
            int r = idx / 12, e = idx - r*12;
            qpl[r][e] = qp[(i0 + r)*144 + h*12 + e];
        }
        __syncthreads();

        const float hwh = log1pf(expf(head_w[h])) * SC_HW;
        const float bbh = bb[h] * SC_B;
        const float mj = mj_l[jl];
        #pragma unroll
        for (int k = 0; k < 8; ++k) {
            const int il = wv*8 + k;
            float qk = 0.f;
            #pragma unroll
            for (int c = 0; c < 16; ++c) qk = fmaf(ktl[jl][c], ql[il][c], qk);
            float d2 = 0.f;
            #pragma unroll
            for (int e = 0; e < 12; ++e) { float d = qpl[il][e] - kpl[jl][e]; d2 = fmaf(d, d, d2); }
            float mt = 1e9f * (mi_l[il]*mj - 1.0f);
            float lg = fmaf(qk, SC_QK, fmaf(-0.5f*hwh, d2, bbh)) + mt;
            lqd[((size_t)(i0+il)*NN + j0 + jl)*12 + h] = lg;
            float m = lg;
            m = fmaxf(m, __shfl_xor(m, 1, 64));
            m = fmaxf(m, __shfl_xor(m, 2, 64));
            m = fmaxf(m, __shfl_xor(m, 4, 64));
            m = fmaxf(m, __shfl_xor(m, 8, 64));
            m = fmaxf(m, __shfl_xor(m, 16, 64));
            m = fmaxf(m, __shfl_xor(m, 32, 64));
            if (jl == 0) mpl[il][h] = m;
        }
    }
    __syncthreads();
    if (t < 384) {
        int il = t / 12, h = t - il*12;
        mpart[((size_t)h*NN + i0 + il)*12 + blockIdx.x] = mpl[il][h];
    }
}

// ---------------- Kernel C2: FUSED bias + safe-M exp + o_pair/o/o_pt partials ----------------
// grid (768 i, 2 jsegs of 384). z read from HBM exactly once (phase-1); phase-2
// re-reads are L1/L2-hot. p lives only in LDS. Partials to opart/vpart/ssum.
__global__ __launch_bounds__(256) void kfuse(
    const float* __restrict__ z, const float* __restrict__ Wb,
    const float* __restrict__ lqd, const float* __restrict__ mpart,
    const float* __restrict__ vall,
    float* __restrict__ opart, float* __restrict__ vpart, float* __restrict__ ssum)
{
    __shared__ float  M_lds[12];
    __shared__ float  p_lds[12][66];
    __shared__ float2 ofold[4][12][64];     // 24 KB
    __shared__ float  sredL[16][6];

    const int i = blockIdx.x, jseg = blockIdx.y;
    const int t = threadIdx.x, w = t >> 6, l = t & 63;
    const int gid = t >> 4, cl = t & 15;
    const int hhalf = gid & 1, h0 = hhalf * 6, jofs = gid >> 1;

    if (t < 12) {
        const float4* mp = (const float4*)(mpart + ((size_t)t*NN + i)*12);
        float4 a = mp[0], b = mp[1], c = mp[2];
        float m = fmaxf(fmaxf(fmaxf(a.x,a.y), fmaxf(a.z,a.w)),
                 fmaxf(fmaxf(fmaxf(b.x,b.y), fmaxf(b.z,b.w)),
                       fmaxf(fmaxf(c.x,c.y), fmaxf(c.z,c.w))));
        M_lds[t] = m + MSLACK;
    }

    // Wb fragment: heads h0..h0+5, channels cl*8..cl*8+7  (12 float4 = 48 VGPR)
    float4 wva[6], wvb[6];
    #pragma unroll
    for (int h = 0; h < 6; ++h) {
        const float4* wp = (const float4*)(Wb + (h0+h)*CZ + cl*8);
        wva[h] = wp[0]; wvb[h] = wp[1];
    }

    float2 oa[12];
    #pragma unroll
    for (int h = 0; h < 12; ++h) { oa[h].x = 0.f; oa[h].y = 0.f; }
    float2 vacc; vacc.x = 0.f; vacc.y = 0.f;
    const int vch = 2*t;            // valid for t<240
    const int vh  = (t < 240) ? (vch / 40) : 0;
    float s_acc = 0.f;

    __syncthreads();
    const float Mh = M_lds[h0 + (cl < 6 ? cl : 5)];
    const int jbase = jseg * 384;

    for (int tile = 0; tile < 6; ++tile) {
        const int jt = jbase + tile*64;

        // ---- phase 1: bias dot + p into LDS ----
        {
            const float4* zq0 = (const float4*)(z + ((size_t)i*NN + jt + jofs)*CZ) + cl*2;
            float4 za = zq0[0], zb = zq0[1];
            for (int it = 0; it < 8; ++it) {
                float4 zaN = za, zbN = zb;
                if (it + 1 < 8) {
                    const float4* zq = (const float4*)(z + ((size_t)i*NN + jt + (it+1)*8 + jofs)*CZ) + cl*2;
                    zaN = zq[0]; zbN = zq[1];
                }
                const int j = jt + it*8 + jofs;
                float b0, b1, b2, b3, b4, b5;
                #define BDOT(BV, H)                                \
                    BV = za.x*wva[H].x;                            \
                    BV = fmaf(za.y, wva[H].y, BV);                 \
                    BV = fmaf(za.z, wva[H].z, BV);                 \
                    BV = fmaf(za.w, wva[H].w, BV);                 \
                    BV = fmaf(zb.x, wvb[H].x, BV);                 \
                    BV = fmaf(zb.y, wvb[H].y, BV);                 \
                    BV = fmaf(zb.z, wvb[H].z, BV);                 \
                    BV = fmaf(zb.w, wvb[H].w, BV);
                BDOT(b0, 0) BDOT(b1, 1) BDOT(b2, 2) BDOT(b3, 3) BDOT(b4, 4) BDOT(b5, 5)
                #undef BDOT
                #define BRED(BV)                                   \
                    BV += __shfl_xor(BV, 1, 16);                   \
                    BV += __shfl_xor(BV, 2, 16);                   \
                    BV += __shfl_xor(BV, 4, 16);                   \
                    BV += __shfl_xor(BV, 8, 16);
                BRED(b0) BRED(b1) BRED(b2) BRED(b3) BRED(b4) BRED(b5)
                #undef BRED
                float bsel = b0;
                bsel = (cl == 1) ? b1 : bsel;
                bsel = (cl == 2) ? b2 : bsel;
                bsel = (cl == 3) ? b3 : bsel;
                bsel = (cl == 4) ? b4 : bsel;
                bsel = (cl == 5) ? b5 : bsel;
                if (cl < 6) {
                    float g = fmaf(bsel, SC_B, lqd[((size_t)i*NN + j)*12 + h0 + cl]);
                    float p = __expf(g - Mh);
                    p_lds[h0 + cl][j - jt] = p;
                    s_acc += p;
                }
                za = zaN; zb = zbN;
            }
        }
        __syncthreads();   // p_lds complete for this tile

        // ---- phase 2a: o_pair partial. lane = c2, wave covers j%4==w ----
        {
            const float2* zr2 = (const float2*)(z + (size_t)i*NN*CZ) + l;
            #pragma unroll 4
            for (int jj = 0; jj < 16; ++jj) {
                const int jb = jj*4 + w;
                float2 zv = zr2[(size_t)(jt + jb)*64];
                #pragma unroll
                for (int h = 0; h < 12; ++h) {
                    float pv = p_lds[h][jb];
                    oa[h].x = fmaf(pv, zv.x, oa[h].x);
                    oa[h].y = fmaf(pv, zv.y, oa[h].y);
                }
            }
        }

        // ---- phase 2b: o/o_pt partial. thread = channel pair (t<240) ----
        if (t < 240) {
            const float2* vr = (const float2*)(vall + (size_t)jt*480 + vch);
            #pragma unroll 4
            for (int jb = 0; jb < 64; ++jb) {
                float2 vv = vr[(size_t)jb*240];
                float pv = p_lds[vh][jb];
                vacc.x = fmaf(pv, vv.x, vacc.x);
                vacc.y = fmaf(pv, vv.y, vacc.y);
            }
        }
        __syncthreads();   // p_lds reads done -> next tile may overwrite
    }

    // ---- folds & partial writes ----
    #pragma unroll
    for (int h = 0; h < 12; ++h) ofold[w][h][l] = oa[h];
    if (cl < 6) sredL[gid][cl] = s_acc;
    if (t < 240)
        *((float2*)(vpart + ((size_t)(jseg*NN + i))*480) + t) = vacc;
    __syncthreads();

    float2* opw = (float2*)(opart + ((size_t)(jseg*NN + i))*1536);
    #pragma unroll
    for (int k = 0; k < 3; ++k) {
        int slot = k*256 + t;
        int h = slot >> 6, c2 = slot & 63;
        float2 v0 = ofold[0][h][c2], v1 = ofold[1][h][c2];
        float2 v2 = ofold[2][h][c2], v3 = ofold[3][h][c2];
        float2 o;
        o.x = v0.x + v1.x + v2.x + v3.x;
        o.y = v0.y + v1.y + v2.y + v3.y;
        opw[slot] = o;
    }
    if (t < 12) {
        float sv = 0.f;
        #pragma unroll
        for (int k = 0; k < 8; ++k) sv += sredL[k*2 + (t/6)][t % 6];
        ssum[(size_t)(jseg*12 + t)*NN + i] = sv;
    }
}

// ---------------- Kernel C3: combine partials, normalize, epilogue ----------------
__global__ __launch_bounds__(256) void kepi(
    const float* __restrict__ opart, const float* __restrict__ vpart,
    const float* __restrict__ ssum, const float* __restrict__ rot,
    const float* __restrict__ trans, float* __restrict__ cat)
{
    __shared__ float sinv[12];
    __shared__ float optl[12][24];
    __shared__ float R[9], T[3];
    const int i = blockIdx.x, t = threadIdx.x;
    if (t < 9) R[t] = rot[i*9 + t];
    if (t < 3) T[t] = trans[i*3 + t];
    if (t >= 16 && t < 28) {
        int h = t - 16;
        sinv[h] = 1.0f / (ssum[(size_t)h*NN + i] + ssum[(size_t)(12+h)*NN + i]);
    }
    __syncthreads();

    float* crow = cat + (size_t)i*OUTIN;
    const float2* op0 = (const float2*)(opart + (size_t)i*1536);
    const float2* op1 = (const float2*)(opart + (size_t)(NN + i)*1536);
    #pragma unroll
    for (int k = 0; k < 3; ++k) {
        int slot = k*256 + t;
        int h = slot >> 6, c2 = slot & 63;
        float2 a = op0[slot], b = op1[slot];
        float sc = sinv[h];
        float2 o; o.x = (a.x + b.x)*sc; o.y = (a.y + b.y)*sc;
        *(float2*)(crow + 576 + h*128 + c2*2) = o;
    }
    if (t < 240) {
        const int ch = 2*t, h = ch/40, e = ch%40;
        float2 v0 = *(const float2*)(vpart + (size_t)i*480 + ch);
        float2 v1 = *(const float2*)(vpart + (size_t)(NN + i)*480 + ch);
        float sc = sinv[h];
        float vx = (v0.x + v1.x)*sc, vy = (v0.y + v1.y)*sc;
        if (e < 16) { crow[h*16 + e] = vx; crow[h*16 + e + 1] = vy; }
        else        { optl[h][e-16] = vx; optl[h][e-15] = vy; }
    }
    __syncthreads();
    if (t < 96) {
        int h = t >> 3, pp = t & 7;
        float wx = optl[h][pp*3+0] - T[0];
        float wy = optl[h][pp*3+1] - T[1];
        float wz = optl[h][pp*3+2] - T[2];
        crow[192 + 0*96 + h*8 + pp] = R[0]*wx + R[3]*wy + R[6]*wz;
        crow[192 + 1*96 + h*8 + pp] = R[1]*wx + R[4]*wy + R[7]*wz;
        crow[192 + 2*96 + h*8 + pp] = R[2]*wx + R[5]*wy + R[8]*wz;
        crow[480 + h*8 + pp] = sqrtf(fmaf(wx,wx,fmaf(wy,wy,wz*wz)) + 1e-8f);
    }
}

// ---------------- Kernel D1: out partial = cat-tile @ Wout-tile^T (split-K) ----------------
__global__ __launch_bounds__(256) void koutp(
    const float* __restrict__ cat, const float* __restrict__ Wout,
    float* __restrict__ ptmp)
{
    __shared__ float ct[32][36];
    __shared__ float wt[64][36];
    const int n0 = blockIdx.x * 32, o0 = blockIdx.y * 64;
    const int k0 = blockIdx.z * 352;
    const int t = threadIdx.x;
    const int tn = (t >> 4) * 2;
    const int to = t & 15;

    float a00=0,a01=0,a02=0,a03=0, a10=0,a11=0,a12=0,a13=0;

    for (int c = 0; c < 11; ++c) {
        __syncthreads();
        #pragma unroll
        for (int u = 0; u < 4; ++u) {
            int idx = u*256 + t, r = idx >> 5, cc = idx & 31;
            ct[r][cc] = cat[(size_t)(n0 + r)*OUTIN + k0 + c*32 + cc];
        }
        #pragma unroll
        for (int u = 0; u < 8; ++u) {
            int idx = u*256 + t, r = idx >> 5, cc = idx & 31;
            wt[r][cc] = Wout[(size_t)(o0 + r)*OUTIN + k0 + c*32 + cc];
        }
        __syncthreads();
        #pragma unroll
        for (int kk = 0; kk < 32; kk += 4) {
            float4 c0 = *(const float4*)&ct[tn][kk];
            float4 c1 = *(const float4*)&ct[tn+1][kk];
            float4 w0 = *(const float4*)&wt[to][kk];
            float4 w1 = *(const float4*)&wt[to+16][kk];
            float4 w2 = *(const float4*)&wt[to+32][kk];
            float4 w3 = *(const float4*)&wt[to+48][kk];
            a00 = fmaf(c0.x,w0.x,a00); a00 = fmaf(c0.y,w0.y,a00); a00 = fmaf(c0.z,w0.z,a00); a00 = fmaf(c0.w,w0.w,a00);
            a01 = fmaf(c0.x,w1.x,a01); a01 = fmaf(c0.y,w1.y,a01); a01 = fmaf(c0.z,w1.z,a01); a01 = fmaf(c0.w,w1.w,a01);
            a02 = fmaf(c0.x,w2.x,a02); a02 = fmaf(c0.y,w2.y,a02); a02 = fmaf(c0.z,w2.z,a02); a02 = fmaf(c0.w,w2.w,a02);
            a03 = fmaf(c0.x,w3.x,a03); a03 = fmaf(c0.y,w3.y,a03); a03 = fmaf(c0.z,w3.z,a03); a03 = fmaf(c0.w,w3.w,a03);
            a10 = fmaf(c1.x,w0.x,a10); a10 = fmaf(c1.y,w0.y,a10); a10 = fmaf(c1.z,w0.z,a10); a10 = fmaf(c1.w,w0.w,a10);
            a11 = fmaf(c1.x,w1.x,a11); a11 = fmaf(c1.y,w1.y,a11); a11 = fmaf(c1.z,w1.z,a11); a11 = fmaf(c1.w,w1.w,a11);
            a12 = fmaf(c1.x,w2.x,a12); a12 = fmaf(c1.y,w2.y,a12); a12 = fmaf(c1.z,w2.z,a12); a12 = fmaf(c1.w,w2.w,a12);
            a13 = fmaf(c1.x,w3.x,a13); a13 = fmaf(c1.y,w3.y,a13); a13 = fmaf(c1.z,w3.z,a13); a13 = fmaf(c1.w,w3.w,a13);
        }
    }
    float* pb = ptmp + (size_t)blockIdx.z * (NN*384);
    pb[(size_t)(n0+tn+0)*384 + o0+to+ 0] = a00;
    pb[(size_t)(n0+tn+0)*384 + o0+to+16] = a01;
    pb[(size_t)(n0+tn+0)*384 + o0+to+32] = a02;
    pb[(size_t)(n0+tn+0)*384 + o0+to+48] = a03;
    pb[(size_t)(n0+tn+1)*384 + o0+to+ 0] = a10;
    pb[(size_t)(n0+tn+1)*384 + o0+to+16] = a11;
    pb[(size_t)(n0+tn+1)*384 + o0+to+32] = a12;
    pb[(size_t)(n0+tn+1)*384 + o0+to+48] = a13;
}

// ---------------- Kernel D2: reduce split-K partials + bias ----------------
__global__ __launch_bounds__(256) void kred(
    const float* __restrict__ ptmp, const float* __restrict__ bout,
    float* __restrict__ out)
{
    int idx = blockIdx.x * 256 + threadIdx.x;
    int o = idx % 384;
    float v = bout[o];
    #pragma unroll
    for (int s = 0; s < 6; ++s) v += ptmp[(size_t)s*(NN*384) + idx];
    out[idx] = v;
}

extern "C" void kernel_launch(void* const* d_in, const int* in_sizes, int n_in,
                              void* d_out, int out_size, void* d_ws, size_t ws_size,
                              hipStream_t stream) {
    const float* s      = (const float*)d_in[0];
    const float* z      = (const float*)d_in[1];
    const float* rot    = (const float*)d_in[2];
    const float* trans  = (const float*)d_in[3];
    const float* mask   = (const float*)d_in[4];
    const float* Wq     = (const float*)d_in[5];
    const float* bq     = (const float*)d_in[6];
    const float* Wkv    = (const float*)d_in[7];
    const float* bkv    = (const float*)d_in[8];
    const float* Wqp    = (const float*)d_in[9];
    const float* bqp    = (const float*)d_in[10];
    const float* Wkvp   = (const float*)d_in[11];
    const float* bkvp   = (const float*)d_in[12];
    const float* Wb     = (const float*)d_in[13];
    const float* bb     = (const float*)d_in[14];
    const float* head_w = (const float*)d_in[15];
    const float* Wout   = (const float*)d_in[16];
    const float* bout   = (const float*)d_in[17];
    float* out = (float*)d_out;
    float* ws  = (float*)d_ws;

    float* q     = ws;              // 147456
    float* kT    = ws + 147456;     // 147456
    float* kpT   = ws + 294912;     // 110592
    float* vall  = ws + 405504;     // 768*480 = 368640
    float* qp    = ws + 774144;     // 110592
    float* qpr   = ws + 884736;     // 110592
    float* kvpr  = ws + 995328;     // 331776
    float* mpart = ws + 1327104;    // 110592
    float* ssum  = ws + 1437696;    // 2*12*768 = 18432
    float* cat   = ws + 1456128;    // 1622016
    float* lqd   = ws + 3078144;    // 7077888 [i][j][12]
    float* opart = ws + 10156032;   // 2*768*1536 = 2359296
    float* vpart = ws + 12515328;   // 2*768*480 = 737280
    float* ptmp  = ws + 13252608;   // 1769472

    kproj<<<dim3(96, 9), 256, 0, stream>>>(s, Wq, bq, Wkv, bkv, Wqp, bqp, Wkvp, bkvp,
                                           q, kT, vall, qpr, kvpr);
    krot<<<dim3(768), 192, 0, stream>>>(rot, trans, qpr, kvpr, qp, kpT, vall);
    kqk<<<dim3(12, 24), 256, 0, stream>>>(kT, kpT, q, qp, mask, head_w, bb, lqd, mpart);
    kfuse<<<dim3(768, 2), 256, 0, stream>>>(z, Wb, lqd, mpart, vall, opart, vpart, ssum);
    kepi<<<dim3(768), 256, 0, stream>>>(opart, vpart, ssum, rot, trans, cat);
    koutp<<<dim3(24, 6, 6), 256, 0, stream>>>(cat, Wout, ptmp);
    kred<<<dim3(1152), 256, 0, stream>>>(ptmp, bout, out);
}